// Round 6
// baseline (419.645 us; speedup 1.0000x reference)
//
#include <hip/hip_runtime.h>
#include <hip/hip_bf16.h>
#include <cstdint>
#include <cstddef>

#define SCALE_ 0.125f
// B=16 N=256 C=512 H=8 HD=64 E=64

typedef float f4_ __attribute__((ext_vector_type(4)));

__device__ __forceinline__ unsigned pk2(float a, float b) {
  union { __hip_bfloat16 h[2]; unsigned u; } x;
  x.h[0] = __float2bfloat16(a);
  x.h[1] = __float2bfloat16(b);
  return x.u;
}
__device__ __forceinline__ unsigned short bf16b(float a) {
  union { __hip_bfloat16 h; unsigned short s; } x;
  x.h = __float2bfloat16(a);
  return x.s;
}
__device__ __forceinline__ float blo(unsigned u) { return __uint_as_float(u << 16); }
__device__ __forceinline__ float bhi(unsigned u) { return __uint_as_float(u & 0xffff0000u); }

// ---------------- Kernel 1: QKV projection GEMM (f32 in, bf16 out) ----------
// X[4096][512] ; W[1536][512] (row-major, y = x @ W^T)
// qb : bf16  [BH][N][64]
// ktq: uint2 [BH][16][256]  entry (d4,y) = 4 consecutive d for key col y
// vq : uint2 [BH][64][64]   entry (y4,d) = 4 consecutive y for dim d
__global__ __launch_bounds__(256) void qkv_gemm(
    const float* __restrict__ X, const float* __restrict__ W,
    unsigned short* __restrict__ qb, uint2* __restrict__ ktq, uint2* __restrict__ vq)
{
  __shared__ alignas(16) float A_s[16][136];
  __shared__ alignas(16) float W_s[16][72];
  const int t  = threadIdx.x;
  const int m0 = blockIdx.x * 128;
  const int o0 = blockIdx.y * 64;
  const int tm = (t & 15) * 8;
  const int to = (t >> 4) * 4;
  float acc[8][4];
  #pragma unroll
  for (int i = 0; i < 8; i++)
    #pragma unroll
    for (int j = 0; j < 4; j++) acc[i][j] = 0.f;

  const float4* X4 = (const float4*)X;
  const float4* W4 = (const float4*)W;
  for (int c0 = 0; c0 < 512; c0 += 16) {
    #pragma unroll
    for (int i = 0; i < 2; i++) {
      int id = t + 256 * i;
      int row = id >> 2, quad = id & 3;
      float4 a = X4[(size_t)(m0 + row) * 128 + (c0 >> 2) + quad];
      A_s[quad*4+0][row] = a.x; A_s[quad*4+1][row] = a.y;
      A_s[quad*4+2][row] = a.z; A_s[quad*4+3][row] = a.w;
    }
    {
      int row = t >> 2, quad = t & 3;
      float4 w = W4[(size_t)(o0 + row) * 128 + (c0 >> 2) + quad];
      W_s[quad*4+0][row] = w.x; W_s[quad*4+1][row] = w.y;
      W_s[quad*4+2][row] = w.z; W_s[quad*4+3][row] = w.w;
    }
    __syncthreads();
    #pragma unroll
    for (int kk = 0; kk < 16; kk++) {
      float4 a0 = *(const float4*)&A_s[kk][tm];
      float4 a1 = *(const float4*)&A_s[kk][tm + 4];
      float4 w0 = *(const float4*)&W_s[kk][to];
      float am[8] = {a0.x,a0.y,a0.z,a0.w,a1.x,a1.y,a1.z,a1.w};
      float wn[4] = {w0.x,w0.y,w0.z,w0.w};
      #pragma unroll
      for (int i = 0; i < 8; i++)
        #pragma unroll
        for (int j = 0; j < 4; j++) acc[i][j] += am[i] * wn[j];
    }
    __syncthreads();
  }
  const int three = o0 >> 9;
  const int h = (o0 >> 6) & 7;
  if (three == 0) {
    #pragma unroll
    for (int i = 0; i < 8; i++) {
      int m = m0 + tm + i;
      int b = m >> 8, n = m & 255;
      unsigned u0 = pk2(acc[i][0], acc[i][1]);
      unsigned u1 = pk2(acc[i][2], acc[i][3]);
      *(uint2*)&qb[((size_t)(b*8 + h)*256 + n)*64 + to] = make_uint2(u0, u1);
    }
  } else if (three == 1) {
    #pragma unroll
    for (int i = 0; i < 8; i++) {
      int m = m0 + tm + i;
      int b = m >> 8, n = m & 255;
      ktq[(size_t)(b*8 + h)*4096 + (size_t)(to >> 2)*256 + n] =
        make_uint2(pk2(acc[i][0], acc[i][1]), pk2(acc[i][2], acc[i][3]));
    }
  } else {
    int m = m0 + tm;                 // multiple of 8 -> same b for 8 rows
    int b = m >> 8, n0 = m & 255;
    #pragma unroll
    for (int ii = 0; ii < 2; ii++) {
      #pragma unroll
      for (int j = 0; j < 4; j++) {
        vq[(size_t)(b*8 + h)*4096 + (size_t)((n0 >> 2) + ii)*64 + to + j] =
          make_uint2(pk2(acc[4*ii+0][j], acc[4*ii+1][j]),
                     pk2(acc[4*ii+2][j], acc[4*ii+3][j]));
      }
    }
  }
}

// ---------------- Kernel 2: fused attn + edge pipeline (8-row tile) ---------
// block = (b, 8 query rows x0..x0+7); 1024 threads = 16 waves.
// Phases 2-3/4.5: thread t -> y = t&255, xq = t>>8 (owns rows 2xq, 2xq+1).
// Phase 4 (PV):   thread t -> x = t>>7, h = (t>>4)&7, d4 = t&15.
// Phase 5 (edge): wave w   -> x-row w&7, e-parity w>>3; lane -> 4 y.
// Phase 6 (fc):   thread t -> x = t>>7, 4 c's.
__global__ __launch_bounds__(1024) void fused_attn(
    const unsigned short* __restrict__ qb, const uint2* __restrict__ ktq,
    const uint2* __restrict__ vq,
    const float* __restrict__ edge, const unsigned char* __restrict__ mask,
    const float* __restrict__ rw, const float* __restrict__ rb,
    const float* __restrict__ ew, const float* __restrict__ eb,
    const float* __restrict__ fcw, const float* __restrict__ fcb,
    float* __restrict__ out_edge, unsigned short* __restrict__ tmpb)
{
  __shared__ alignas(16) unsigned short q_sb[8][8][64];   // 8 KB bf16 q
  __shared__ alignas(16) unsigned short p_sb[8][8][256];  // 32 KB: p (exp), later t8
  __shared__ alignas(16) float nacc_s[8][512];            // 16 KB PV result
  __shared__ alignas(16) float rw_s[64][8];
  __shared__ alignas(16) float ew_s[64][8];
  __shared__ alignas(16) float eb_s[64];
  __shared__ alignas(16) unsigned char mkb[8][256];       // mask bytes
  __shared__ alignas(16) float redm[64][4];
  __shared__ alignas(16) float redsum[64][4];
  __shared__ alignas(16) float pl_s[8][64];

  const int t = threadIdx.x;
  const int lane = t & 63;
  const int wv = t >> 6;
  const int bid = blockIdx.x;
  const int b = bid >> 5;
  const int x0 = (bid & 31) * 8;

  // ---- phase 1: stage q (bf16), weights, mask bytes
  for (int i = t; i < 2048; i += 1024) {
    int xi = i >> 8, h = (i >> 5) & 7, d2 = i & 31;
    ((unsigned*)q_sb)[i] =
      *(const unsigned*)&qb[((size_t)(b*8 + h)*256 + x0 + xi)*64 + d2*2];
  }
  if (t < 512) rw_s[t >> 3][t & 7] = rw[(t & 7)*64 + (t >> 3)];
  if (t < 512) ((float*)ew_s)[t] = ew[t];
  if (t < 64) eb_s[t] = eb[t];
  if (t < 512)
    ((unsigned*)mkb)[t] =
      ((const unsigned*)(mask + (size_t)b*65536 + (size_t)x0*256))[t];
  __syncthreads();

  const int y = t & 255;
  const int xq = t >> 8;           // 0..3, owns rows 2xq, 2xq+1

  // ---- phase 2a: edge bias (HBM/L3 stream; block touches 8KB per e)
  float acc[2][8];
  #pragma unroll
  for (int h = 0; h < 8; h++) { float rv = rb[h]; acc[0][h] = rv; acc[1][h] = rv; }
  {
    const float* ep = edge + (size_t)b*4194304 + (size_t)(x0 + 2*xq)*256 + y;
    #pragma unroll 4
    for (int e = 0; e < 64; e++) {
      float v0 = ep[(size_t)e*65536];
      float v1 = ep[(size_t)e*65536 + 256];
      const float4* rwq = (const float4*)rw_s[e];
      float4 w0 = rwq[0], w1 = rwq[1];
      float wh[8] = {w0.x,w0.y,w0.z,w0.w,w1.x,w1.y,w1.z,w1.w};
      #pragma unroll
      for (int h = 0; h < 8; h++) {
        acc[0][h] += v0 * wh[h];
        acc[1][h] += v1 * wh[h];
      }
    }
  }

  // ---- phase 2b: QK^T (k coalesced over y; q broadcast from LDS bf16)
  #pragma unroll 2
  for (int h = 0; h < 8; h++) {
    const uint2* kq = ktq + (size_t)(b*8 + h)*4096 + y;
    const uint4* qA = (const uint4*)&q_sb[2*xq][h][0];
    const uint4* qB = (const uint4*)&q_sb[2*xq+1][h][0];
    float qk0 = 0.f, qk1 = 0.f;
    #pragma unroll
    for (int d8 = 0; d8 < 8; d8++) {
      uint4 ua = qA[d8], ub = qB[d8];
      uint2 k0 = kq[(size_t)(2*d8)*256];
      uint2 k1 = kq[(size_t)(2*d8+1)*256];
      float kv[8] = {blo(k0.x),bhi(k0.x),blo(k0.y),bhi(k0.y),
                     blo(k1.x),bhi(k1.x),blo(k1.y),bhi(k1.y)};
      float qa[8] = {blo(ua.x),bhi(ua.x),blo(ua.y),bhi(ua.y),
                     blo(ua.z),bhi(ua.z),blo(ua.w),bhi(ua.w)};
      float qbv[8] = {blo(ub.x),bhi(ub.x),blo(ub.y),bhi(ub.y),
                      blo(ub.z),bhi(ub.z),blo(ub.w),bhi(ub.w)};
      #pragma unroll
      for (int j = 0; j < 8; j++) { qk0 += qa[j]*kv[j]; qk1 += qbv[j]*kv[j]; }
    }
    acc[0][h] += SCALE_ * qk0;
    acc[1][h] += SCALE_ * qk1;
  }

  // ---- phase 3: softmax (wave shfl + cross-wave combine over y-quarters)
  float p[2][8];
  float madd[2];
  madd[0] = mkb[2*xq][y]     ? -1e30f : 0.f;
  madd[1] = mkb[2*xq + 1][y] ? -1e30f : 0.f;
  #pragma unroll
  for (int r = 0; r < 2; r++)
    #pragma unroll
    for (int h = 0; h < 8; h++) {
      float v = acc[r][h] + madd[r];
      p[r][h] = v;
      #pragma unroll
      for (int off = 32; off; off >>= 1) v = fmaxf(v, __shfl_xor(v, off, 64));
      if (lane == 0) redm[(2*xq + r)*8 + h][wv & 3] = v;
    }
  __syncthreads();
  #pragma unroll
  for (int r = 0; r < 2; r++)
    #pragma unroll
    for (int h = 0; h < 8; h++) {
      int R = (2*xq + r)*8 + h;
      float4 rm = *(const float4*)&redm[R][0];
      float mx = fmaxf(fmaxf(rm.x, rm.y), fmaxf(rm.z, rm.w));
      float pe = __expf(p[r][h] - mx);
      p[r][h] = pe;
      float s = pe;
      #pragma unroll
      for (int off = 32; off; off >>= 1) s += __shfl_xor(s, off, 64);
      if (lane == 0) redsum[R][wv & 3] = s;
      p_sb[2*xq + r][h][y] = bf16b(pe);
    }
  __syncthreads();

  // ---- phase 4: PV. thread -> (x4, h4, 4 d's); p from LDS, v from global
  {
    const int x4 = t >> 7;
    const int h4 = (t >> 4) & 7;
    const int d4 = t & 15;
    const uint2* vp = vq + (size_t)(b*8 + h4)*4096 + d4*4;
    float a4[4] = {0.f, 0.f, 0.f, 0.f};
    #pragma unroll 4
    for (int y4 = 0; y4 < 64; y4++) {
      uint2 pv_ = *(const uint2*)&p_sb[x4][h4][y4*4];
      float pj[4] = {blo(pv_.x), bhi(pv_.x), blo(pv_.y), bhi(pv_.y)};
      #pragma unroll
      for (int j = 0; j < 4; j++) {
        uint2 uv = vp[(size_t)y4*64 + j];
        float v0 = blo(uv.x), v1 = bhi(uv.x), v2 = blo(uv.y), v3 = bhi(uv.y);
        a4[j] += pj[0]*v0 + pj[1]*v1 + pj[2]*v2 + pj[3]*v3;
      }
    }
    int R4 = x4*8 + h4;
    float4 rs = *(const float4*)&redsum[R4][0];
    float inv = 1.0f / (rs.x + rs.y + rs.z + rs.w);
    float4 o;
    o.x = a4[0]*inv; o.y = a4[1]*inv; o.z = a4[2]*inv; o.w = a4[3]*inv;
    *(float4*)&nacc_s[x4][h4*64 + d4*4] = o;
  }
  __syncthreads();   // PV done reading p_sb; nacc ready

  // ---- phase 4.5: overwrite p_sb with t8 = attn_sm + residual (bf16)
  #pragma unroll
  for (int r = 0; r < 2; r++)
    #pragma unroll
    for (int h = 0; h < 8; h++) {
      int R = (2*xq + r)*8 + h;
      float4 rs = *(const float4*)&redsum[R][0];
      float inv = 1.0f / (rs.x + rs.y + rs.z + rs.w);
      p_sb[2*xq + r][h][y] = bf16b(p[r][h]*inv + acc[r][h]);
    }
  __syncthreads();

  // ---- phase 5: expand + edge_out write + pooling (wave-local, NO barriers)
  {
    const int xi5 = wv & 7;
    const int epar = wv >> 3;
    const int y0 = lane * 4;
    const int xg = x0 + xi5;
    uchar4 mb = *(const uchar4*)&mkb[xi5][y0];
    const float md0 = mb.x ? -1e30f : 0.f;
    const float md1 = mb.y ? -1e30f : 0.f;
    const float md2 = mb.z ? -1e30f : 0.f;
    const float md3 = mb.w ? -1e30f : 0.f;
    const float4* ew4 = (const float4*)ew_s;
    for (int ec = 0; ec < 32; ec++) {
      int e = ec*2 + epar;
      float4 w0 = ew4[e*2], w1 = ew4[e*2+1];
      float wh[8] = {w0.x,w0.y,w0.z,w0.w,w1.x,w1.y,w1.z,w1.w};
      float ebv = eb_s[e];
      float eo0 = ebv, eo1 = ebv, eo2 = ebv, eo3 = ebv;
      #pragma unroll
      for (int h = 0; h < 8; h++) {
        uint2 tv = *(const uint2*)&p_sb[xi5][h][y0];
        eo0 += blo(tv.x)*wh[h];
        eo1 += bhi(tv.x)*wh[h];
        eo2 += blo(tv.y)*wh[h];
        eo3 += bhi(tv.y)*wh[h];
      }
      float b0 = eo0+md0, b1 = eo1+md1, b2 = eo2+md2, b3 = eo3+md3;
      float mx = fmaxf(fmaxf(b0, b1), fmaxf(b2, b3));
      #pragma unroll
      for (int off = 32; off; off >>= 1) mx = fmaxf(mx, __shfl_xor(mx, off, 64));
      float e0 = __expf(b0-mx), e1 = __expf(b1-mx), e2 = __expf(b2-mx), e3 = __expf(b3-mx);
      float se  = e0 + e1 + e2 + e3;
      float swe = e0*eo0 + e1*eo1 + e2*eo2 + e3*eo3;
      #pragma unroll
      for (int off = 32; off; off >>= 1) {
        se  += __shfl_xor(se, off, 64);
        swe += __shfl_xor(swe, off, 64);
      }
      if (lane == 0) pl_s[xi5][e] = swe / se;
      f4_ ov = {eo0, eo1, eo2, eo3};
      __builtin_nontemporal_store(ov,
        (f4_*)&out_edge[((size_t)(b*64 + e)*256 + xg)*256 + y0]);
    }
  }
  __syncthreads();

  // ---- phase 6: node_tmp = PV + pool @ fc_w^T + fc_b  (bf16 out)
  {
    const int xi6 = t >> 7;
    const int c4 = (t & 127) * 4;
    const int xg = x0 + xi6;
    float4 a = *(const float4*)&nacc_s[xi6][c4];
    float4 bias = *(const float4*)&fcb[c4];
    a.x += bias.x; a.y += bias.y; a.z += bias.z; a.w += bias.w;
    const float4* fw4 = (const float4*)fcw;
    #pragma unroll 4
    for (int e4 = 0; e4 < 16; e4++) {
      float4 pl4 = *(const float4*)&pl_s[xi6][e4*4];
      float4 f0 = fw4[(size_t)(c4+0)*16 + e4];
      float4 f1 = fw4[(size_t)(c4+1)*16 + e4];
      float4 f2 = fw4[(size_t)(c4+2)*16 + e4];
      float4 f3 = fw4[(size_t)(c4+3)*16 + e4];
      a.x += pl4.x*f0.x + pl4.y*f0.y + pl4.z*f0.z + pl4.w*f0.w;
      a.y += pl4.x*f1.x + pl4.y*f1.y + pl4.z*f1.z + pl4.w*f1.w;
      a.z += pl4.x*f2.x + pl4.y*f2.y + pl4.z*f2.z + pl4.w*f2.w;
      a.w += pl4.x*f3.x + pl4.y*f3.y + pl4.z*f3.z + pl4.w*f3.w;
    }
    *(uint2*)&tmpb[((size_t)b*256 + xg)*512 + c4] =
      make_uint2(pk2(a.x, a.y), pk2(a.z, a.w));
  }
}

// ---------------- Kernel 3: output projection GEMM + bias (bf16 in) ---------
__global__ __launch_bounds__(256) void proj_gemm(
    const unsigned short* __restrict__ Xb, const float* __restrict__ W,
    const float* __restrict__ bias, float* __restrict__ out)
{
  __shared__ alignas(16) float A_s[16][136];
  __shared__ alignas(16) float W_s[16][72];
  const int t  = threadIdx.x;
  const int m0 = blockIdx.x * 128;
  const int o0 = blockIdx.y * 64;
  const int tm = (t & 15) * 8;
  const int to = (t >> 4) * 4;
  float acc[8][4];
  #pragma unroll
  for (int i = 0; i < 8; i++)
    #pragma unroll
    for (int j = 0; j < 4; j++) acc[i][j] = 0.f;

  const uint4* X4 = (const uint4*)Xb;
  const float4* W4 = (const float4*)W;
  for (int c0 = 0; c0 < 512; c0 += 16) {
    {
      int row = t >> 1, half = t & 1;
      uint4 a = X4[(size_t)(m0 + row) * 64 + (c0 >> 3) + half];
      int cb = half*8;
      A_s[cb+0][row] = blo(a.x); A_s[cb+1][row] = bhi(a.x);
      A_s[cb+2][row] = blo(a.y); A_s[cb+3][row] = bhi(a.y);
      A_s[cb+4][row] = blo(a.z); A_s[cb+5][row] = bhi(a.z);
      A_s[cb+6][row] = blo(a.w); A_s[cb+7][row] = bhi(a.w);
    }
    {
      int row = t >> 2, quad = t & 3;
      float4 w = W4[(size_t)(o0 + row) * 128 + (c0 >> 2) + quad];
      W_s[quad*4+0][row] = w.x; W_s[quad*4+1][row] = w.y;
      W_s[quad*4+2][row] = w.z; W_s[quad*4+3][row] = w.w;
    }
    __syncthreads();
    #pragma unroll
    for (int kk = 0; kk < 16; kk++) {
      float4 a0 = *(const float4*)&A_s[kk][tm];
      float4 a1 = *(const float4*)&A_s[kk][tm + 4];
      float4 w0 = *(const float4*)&W_s[kk][to];
      float am[8] = {a0.x,a0.y,a0.z,a0.w,a1.x,a1.y,a1.z,a1.w};
      float wn[4] = {w0.x,w0.y,w0.z,w0.w};
      #pragma unroll
      for (int i = 0; i < 8; i++)
        #pragma unroll
        for (int j = 0; j < 4; j++) acc[i][j] += am[i] * wn[j];
    }
    __syncthreads();
  }
  float4 bb = *(const float4*)&bias[o0 + to];
  #pragma unroll
  for (int i = 0; i < 8; i++) {
    int m = m0 + tm + i;
    float4 r = make_float4(acc[i][0]+bb.x, acc[i][1]+bb.y, acc[i][2]+bb.z, acc[i][3]+bb.w);
    *(float4*)&out[(size_t)m*512 + o0 + to] = r;
  }
}

extern "C" void kernel_launch(void* const* d_in, const int* in_sizes, int n_in,
                              void* d_out, int out_size, void* d_ws, size_t ws_size,
                              hipStream_t stream)
{
  (void)in_sizes; (void)n_in; (void)out_size; (void)ws_size;
  const float* node   = (const float*)d_in[0];
  const float* edge   = (const float*)d_in[1];
  const unsigned char* mask = (const unsigned char*)d_in[2];
  const float* qkv_w  = (const float*)d_in[3];
  const float* proj_w = (const float*)d_in[4];
  const float* proj_b = (const float*)d_in[5];
  const float* rw     = (const float*)d_in[6];
  const float* rb     = (const float*)d_in[7];
  const float* ew     = (const float*)d_in[8];
  const float* eb     = (const float*)d_in[9];
  const float* fcw    = (const float*)d_in[10];
  const float* fcb    = (const float*)d_in[11];

  float* out_node = (float*)d_out;
  float* out_edge = out_node + (size_t)16*256*512;

  // workspace: 16 MB total (bf16 intermediates)
  char* ws = (char*)d_ws;
  unsigned short* qb  = (unsigned short*)(ws);                    // 4 MB
  uint2*          ktq = (uint2*)         (ws + 4u*1024*1024);     // 4 MB
  uint2*          vq  = (uint2*)         (ws + 8u*1024*1024);     // 4 MB
  unsigned short* tmpb= (unsigned short*)(ws + 12u*1024*1024);    // 4 MB

  qkv_gemm <<<dim3(32, 24, 1), 256, 0, stream>>>(node, qkv_w, qb, ktq, vq);
  fused_attn<<<dim3(512, 1, 1), 1024, 0, stream>>>(qb, ktq, vq, edge, mask,
                                                   rw, rb, ew, eb, fcw, fcb,
                                                   out_edge, tmpb);
  proj_gemm<<<dim3(32, 8, 1), 256, 0, stream>>>(tmpb, proj_w, proj_b, out_node);
}

// Round 7
// 415.633 us; speedup vs baseline: 1.0097x; 1.0097x over previous
//
#include <hip/hip_runtime.h>
#include <hip/hip_bf16.h>
#include <cstdint>
#include <cstddef>

#define SCALE_ 0.125f
// B=16 N=256 C=512 H=8 HD=64 E=64

typedef float f4_ __attribute__((ext_vector_type(4)));

__device__ __forceinline__ unsigned pk2(float a, float b) {
  union { __hip_bfloat16 h[2]; unsigned u; } x;
  x.h[0] = __float2bfloat16(a);
  x.h[1] = __float2bfloat16(b);
  return x.u;
}
__device__ __forceinline__ unsigned short bf16b(float a) {
  union { __hip_bfloat16 h; unsigned short s; } x;
  x.h = __float2bfloat16(a);
  return x.s;
}
__device__ __forceinline__ float blo(unsigned u) { return __uint_as_float(u << 16); }
__device__ __forceinline__ float bhi(unsigned u) { return __uint_as_float(u & 0xffff0000u); }

// DPP wave64 sum: VALU-pipe reduction (NOT the DS pipe like __shfl_xor).
// After row_shr 1/2/4/8 each row's lane15/31/47/63 holds its row sum;
// row_bcast:15 (rows 1,3) then row_bcast:31 (rows 2,3) accumulate into lane 63.
template<int CTRL, int RM>
__device__ __forceinline__ float dppadd(float v) {
  int x = __builtin_amdgcn_update_dpp(0, __float_as_int(v), CTRL, RM, 0xf, true);
  return v + __int_as_float(x);
}
__device__ __forceinline__ float wave_sum64(float v) {
  v = dppadd<0x111, 0xf>(v);   // row_shr:1
  v = dppadd<0x112, 0xf>(v);   // row_shr:2
  v = dppadd<0x114, 0xf>(v);   // row_shr:4
  v = dppadd<0x118, 0xf>(v);   // row_shr:8
  v = dppadd<0x142, 0xa>(v);   // row_bcast:15 -> rows 1,3
  v = dppadd<0x143, 0xc>(v);   // row_bcast:31 -> rows 2,3
  return __int_as_float(__builtin_amdgcn_readlane(__float_as_int(v), 63));
}

// ---------------- Kernel 1: QKV projection GEMM (f32 in, bf16 out) ----------
// X[4096][512] ; W[1536][512] (row-major, y = x @ W^T)
// qb : bf16  [BH][N][64]
// ktq: uint2 [BH][16][256]  entry (d4,y) = 4 consecutive d for key col y
// vq : uint2 [BH][64][64]   entry (y4,d) = 4 consecutive y for dim d
__global__ __launch_bounds__(256) void qkv_gemm(
    const float* __restrict__ X, const float* __restrict__ W,
    unsigned short* __restrict__ qb, uint2* __restrict__ ktq, uint2* __restrict__ vq)
{
  __shared__ alignas(16) float A_s[16][136];
  __shared__ alignas(16) float W_s[16][72];
  const int t  = threadIdx.x;
  const int m0 = blockIdx.x * 128;
  const int o0 = blockIdx.y * 64;
  const int tm = (t & 15) * 8;
  const int to = (t >> 4) * 4;
  float acc[8][4];
  #pragma unroll
  for (int i = 0; i < 8; i++)
    #pragma unroll
    for (int j = 0; j < 4; j++) acc[i][j] = 0.f;

  const float4* X4 = (const float4*)X;
  const float4* W4 = (const float4*)W;
  for (int c0 = 0; c0 < 512; c0 += 16) {
    #pragma unroll
    for (int i = 0; i < 2; i++) {
      int id = t + 256 * i;
      int row = id >> 2, quad = id & 3;
      float4 a = X4[(size_t)(m0 + row) * 128 + (c0 >> 2) + quad];
      A_s[quad*4+0][row] = a.x; A_s[quad*4+1][row] = a.y;
      A_s[quad*4+2][row] = a.z; A_s[quad*4+3][row] = a.w;
    }
    {
      int row = t >> 2, quad = t & 3;
      float4 w = W4[(size_t)(o0 + row) * 128 + (c0 >> 2) + quad];
      W_s[quad*4+0][row] = w.x; W_s[quad*4+1][row] = w.y;
      W_s[quad*4+2][row] = w.z; W_s[quad*4+3][row] = w.w;
    }
    __syncthreads();
    #pragma unroll
    for (int kk = 0; kk < 16; kk++) {
      float4 a0 = *(const float4*)&A_s[kk][tm];
      float4 a1 = *(const float4*)&A_s[kk][tm + 4];
      float4 w0 = *(const float4*)&W_s[kk][to];
      float am[8] = {a0.x,a0.y,a0.z,a0.w,a1.x,a1.y,a1.z,a1.w};
      float wn[4] = {w0.x,w0.y,w0.z,w0.w};
      #pragma unroll
      for (int i = 0; i < 8; i++)
        #pragma unroll
        for (int j = 0; j < 4; j++) acc[i][j] += am[i] * wn[j];
    }
    __syncthreads();
  }
  const int three = o0 >> 9;
  const int h = (o0 >> 6) & 7;
  if (three == 0) {
    #pragma unroll
    for (int i = 0; i < 8; i++) {
      int m = m0 + tm + i;
      int b = m >> 8, n = m & 255;
      unsigned u0 = pk2(acc[i][0], acc[i][1]);
      unsigned u1 = pk2(acc[i][2], acc[i][3]);
      *(uint2*)&qb[((size_t)(b*8 + h)*256 + n)*64 + to] = make_uint2(u0, u1);
    }
  } else if (three == 1) {
    #pragma unroll
    for (int i = 0; i < 8; i++) {
      int m = m0 + tm + i;
      int b = m >> 8, n = m & 255;
      ktq[(size_t)(b*8 + h)*4096 + (size_t)(to >> 2)*256 + n] =
        make_uint2(pk2(acc[i][0], acc[i][1]), pk2(acc[i][2], acc[i][3]));
    }
  } else {
    int m = m0 + tm;                 // multiple of 8 -> same b for 8 rows
    int b = m >> 8, n0 = m & 255;
    #pragma unroll
    for (int ii = 0; ii < 2; ii++) {
      #pragma unroll
      for (int j = 0; j < 4; j++) {
        vq[(size_t)(b*8 + h)*4096 + (size_t)((n0 >> 2) + ii)*64 + to + j] =
          make_uint2(pk2(acc[4*ii+0][j], acc[4*ii+1][j]),
                     pk2(acc[4*ii+2][j], acc[4*ii+3][j]));
      }
    }
  }
}

// ---------------- Kernel 2: fused attn + edge pipeline (8-row tile) ---------
// block = (b, 8 query rows); 1024 threads = 16 waves. DS-pipe minimized:
// no shfl trees (DPP + PV-side sums), q from global, t8 reads hoisted.
__global__ __launch_bounds__(1024) void fused_attn(
    const unsigned short* __restrict__ qb, const uint2* __restrict__ ktq,
    const uint2* __restrict__ vq,
    const float* __restrict__ edge, const unsigned char* __restrict__ mask,
    const float* __restrict__ rw, const float* __restrict__ rb,
    const float* __restrict__ ew, const float* __restrict__ eb,
    const float* __restrict__ fcw, const float* __restrict__ fcb,
    float* __restrict__ out_edge, unsigned short* __restrict__ tmpb)
{
  __shared__ alignas(16) unsigned short p_sb[8][8][264];  // 33 KB: p, later t8 (264: bank-skew)
  __shared__ alignas(16) float nacc_s[8][512];            // 16 KB PV result
  __shared__ alignas(16) float rw_s[64][8];
  __shared__ alignas(16) float ew_s[64][8];
  __shared__ alignas(16) float eb_s[64];
  __shared__ alignas(16) unsigned char mkb[8][256];
  __shared__ alignas(16) float sums_s[8][8];
  __shared__ alignas(16) float pl_s[8][64];

  const int t = threadIdx.x;
  const int lane = t & 63;
  const int wv = t >> 6;
  const int b = blockIdx.x >> 5;
  const int x0 = (blockIdx.x & 31) * 8;

  // ---- phase 1: stage small weights + mask bytes (no q staging)
  if (t < 512) rw_s[t >> 3][t & 7] = rw[(t & 7)*64 + (t >> 3)];
  if (t < 512) ((float*)ew_s)[t] = ew[t];
  if (t < 64) eb_s[t] = eb[t];
  if (t < 512)
    ((unsigned*)mkb)[t] =
      ((const unsigned*)(mask + (size_t)b*65536 + (size_t)x0*256))[t];
  __syncthreads();

  const int y = t & 255;
  const int xq = t >> 8;           // 0..3, owns rows 2xq, 2xq+1

  // ---- phase 2a: edge bias (HBM/L3 stream)
  float acc[2][8];
  #pragma unroll
  for (int h = 0; h < 8; h++) { float rv = rb[h]; acc[0][h] = rv; acc[1][h] = rv; }
  {
    const float* ep = edge + (size_t)b*4194304 + (size_t)(x0 + 2*xq)*256 + y;
    #pragma unroll 4
    for (int e = 0; e < 64; e++) {
      float v0 = ep[(size_t)e*65536];
      float v1 = ep[(size_t)e*65536 + 256];
      const float4* rwq = (const float4*)rw_s[e];
      float4 w0 = rwq[0], w1 = rwq[1];
      float wh[8] = {w0.x,w0.y,w0.z,w0.w,w1.x,w1.y,w1.z,w1.w};
      #pragma unroll
      for (int h = 0; h < 8; h++) {
        acc[0][h] += v0 * wh[h];
        acc[1][h] += v1 * wh[h];
      }
    }
  }

  // ---- phase 2b: QK^T (k coalesced over y; q via global broadcast loads)
  #pragma unroll 2
  for (int h = 0; h < 8; h++) {
    const uint2* kq = ktq + (size_t)(b*8 + h)*4096 + y;
    const uint4* qA = (const uint4*)(qb + ((size_t)(b*8 + h)*256 + x0 + 2*xq)*64);
    float qk0 = 0.f, qk1 = 0.f;
    #pragma unroll
    for (int d8 = 0; d8 < 8; d8++) {
      uint4 ua = qA[d8], ub = qA[8 + d8];   // rows 2xq, 2xq+1
      uint2 k0 = kq[(size_t)(2*d8)*256];
      uint2 k1 = kq[(size_t)(2*d8+1)*256];
      float kv[8] = {blo(k0.x),bhi(k0.x),blo(k0.y),bhi(k0.y),
                     blo(k1.x),bhi(k1.x),blo(k1.y),bhi(k1.y)};
      float qa[8] = {blo(ua.x),bhi(ua.x),blo(ua.y),bhi(ua.y),
                     blo(ua.z),bhi(ua.z),blo(ua.w),bhi(ua.w)};
      float qbv[8] = {blo(ub.x),bhi(ub.x),blo(ub.y),bhi(ub.y),
                      blo(ub.z),bhi(ub.z),blo(ub.w),bhi(ub.w)};
      #pragma unroll
      for (int j = 0; j < 8; j++) { qk0 += qa[j]*kv[j]; qk1 += qbv[j]*kv[j]; }
    }
    acc[0][h] += SCALE_ * qk0;
    acc[1][h] += SCALE_ * qk1;
  }

  // ---- phase 3: p = exp(s + mask)  (no max subtraction; no shfl trees)
  const float madd0 = mkb[2*xq][y]     ? -1e30f : 0.f;
  const float madd1 = mkb[2*xq + 1][y] ? -1e30f : 0.f;
  #pragma unroll
  for (int h = 0; h < 8; h++) {
    p_sb[2*xq    ][h][y] = bf16b(__expf(acc[0][h] + madd0));
    p_sb[2*xq + 1][h][y] = bf16b(__expf(acc[1][h] + madd1));
  }
  __syncthreads();

  // ---- phase 4: PV + row sums. thread -> (x4, h4, 4 d's)
  {
    const int x4 = t >> 7;
    const int h4 = (t >> 4) & 7;
    const int d4 = t & 15;
    const uint2* vp = vq + (size_t)(b*8 + h4)*4096 + d4*4;
    float a4[4] = {0.f, 0.f, 0.f, 0.f};
    float psum = 0.f;
    #pragma unroll 4
    for (int y4 = 0; y4 < 64; y4++) {
      uint2 pv_ = *(const uint2*)&p_sb[x4][h4][y4*4];
      float pj0 = blo(pv_.x), pj1 = bhi(pv_.x), pj2 = blo(pv_.y), pj3 = bhi(pv_.y);
      psum += (pj0 + pj1) + (pj2 + pj3);
      #pragma unroll
      for (int j = 0; j < 4; j++) {
        uint2 uv = vp[(size_t)y4*64 + j];
        float v0 = blo(uv.x), v1 = bhi(uv.x), v2 = blo(uv.y), v3 = bhi(uv.y);
        a4[j] += pj0*v0 + pj1*v1 + pj2*v2 + pj3*v3;
      }
    }
    float inv = 1.0f / psum;
    float4 o;
    o.x = a4[0]*inv; o.y = a4[1]*inv; o.z = a4[2]*inv; o.w = a4[3]*inv;
    *(float4*)&nacc_s[x4][h4*64 + d4*4] = o;
    if (d4 == 0) sums_s[x4][h4] = psum;
  }
  __syncthreads();   // PV done reading p_sb; nacc + sums ready

  // ---- phase 4.5: overwrite p_sb with t8 = attn_sm + residual (bf16)
  #pragma unroll
  for (int r = 0; r < 2; r++) {
    float madd = r ? madd1 : madd0;
    #pragma unroll
    for (int h = 0; h < 8; h++) {
      float inv = 1.0f / sums_s[2*xq + r][h];
      float pe = __expf(acc[r][h] + madd);       // recompute (VALU-cheap, saves VGPRs)
      p_sb[2*xq + r][h][y] = bf16b(pe*inv + acc[r][h]);
    }
  }
  __syncthreads();

  // ---- phase 5: expand + edge_out write + pooling (DPP reduce, t8 hoisted)
  {
    const int xi5 = wv & 7;
    const int epar = wv >> 3;
    const int y0 = lane * 4;
    const int xg = x0 + xi5;
    uchar4 mb = *(const uchar4*)&mkb[xi5][y0];
    const float md0 = mb.x ? -1e30f : 0.f;
    const float md1 = mb.y ? -1e30f : 0.f;
    const float md2 = mb.z ? -1e30f : 0.f;
    const float md3 = mb.w ? -1e30f : 0.f;
    uint2 tvh[8];                                 // this lane's t8[h][4y] - read ONCE
    #pragma unroll
    for (int h = 0; h < 8; h++) tvh[h] = *(const uint2*)&p_sb[xi5][h][y0];
    const float4* ew4 = (const float4*)ew_s;
    for (int ec = 0; ec < 32; ec++) {
      int e = ec*2 + epar;
      float4 w0 = ew4[e*2], w1 = ew4[e*2+1];
      float wh[8] = {w0.x,w0.y,w0.z,w0.w,w1.x,w1.y,w1.z,w1.w};
      float ebv = eb_s[e];
      float eo0 = ebv, eo1 = ebv, eo2 = ebv, eo3 = ebv;
      #pragma unroll
      for (int h = 0; h < 8; h++) {
        uint2 tv = tvh[h];
        eo0 += blo(tv.x)*wh[h];
        eo1 += bhi(tv.x)*wh[h];
        eo2 += blo(tv.y)*wh[h];
        eo3 += bhi(tv.y)*wh[h];
      }
      // pooled softmax, no max subtraction (exp(-1e30)=0 for masked)
      float e0 = __expf(eo0+md0), e1 = __expf(eo1+md1);
      float e2 = __expf(eo2+md2), e3 = __expf(eo3+md3);
      float se  = (e0 + e1) + (e2 + e3);
      float swe = (e0*eo0 + e1*eo1) + (e2*eo2 + e3*eo3);
      se  = wave_sum64(se);
      swe = wave_sum64(swe);
      if (lane == 0) pl_s[xi5][e] = swe / se;
      f4_ ov = {eo0, eo1, eo2, eo3};
      __builtin_nontemporal_store(ov,
        (f4_*)&out_edge[((size_t)(b*64 + e)*256 + xg)*256 + y0]);
    }
  }
  __syncthreads();

  // ---- phase 6: node_tmp = PV + pool @ fc_w^T + fc_b  (bf16 out)
  {
    const int xi6 = t >> 7;
    const int c4 = (t & 127) * 4;
    const int xg = x0 + xi6;
    float4 a = *(const float4*)&nacc_s[xi6][c4];
    float4 bias = *(const float4*)&fcb[c4];
    a.x += bias.x; a.y += bias.y; a.z += bias.z; a.w += bias.w;
    const float4* fw4 = (const float4*)fcw;
    #pragma unroll 4
    for (int e4 = 0; e4 < 16; e4++) {
      float4 pl4 = *(const float4*)&pl_s[xi6][e4*4];
      float4 f0 = fw4[(size_t)(c4+0)*16 + e4];
      float4 f1 = fw4[(size_t)(c4+1)*16 + e4];
      float4 f2 = fw4[(size_t)(c4+2)*16 + e4];
      float4 f3 = fw4[(size_t)(c4+3)*16 + e4];
      a.x += pl4.x*f0.x + pl4.y*f0.y + pl4.z*f0.z + pl4.w*f0.w;
      a.y += pl4.x*f1.x + pl4.y*f1.y + pl4.z*f1.z + pl4.w*f1.w;
      a.z += pl4.x*f2.x + pl4.y*f2.y + pl4.z*f2.z + pl4.w*f2.w;
      a.w += pl4.x*f3.x + pl4.y*f3.y + pl4.z*f3.z + pl4.w*f3.w;
    }
    *(uint2*)&tmpb[((size_t)b*256 + xg)*512 + c4] =
      make_uint2(pk2(a.x, a.y), pk2(a.z, a.w));
  }
}

// ---------------- Kernel 3: output projection GEMM + bias (bf16 in) ---------
__global__ __launch_bounds__(256) void proj_gemm(
    const unsigned short* __restrict__ Xb, const float* __restrict__ W,
    const float* __restrict__ bias, float* __restrict__ out)
{
  __shared__ alignas(16) float A_s[16][136];
  __shared__ alignas(16) float W_s[16][72];
  const int t  = threadIdx.x;
  const int m0 = blockIdx.x * 128;
  const int o0 = blockIdx.y * 64;
  const int tm = (t & 15) * 8;
  const int to = (t >> 4) * 4;
  float acc[8][4];
  #pragma unroll
  for (int i = 0; i < 8; i++)
    #pragma unroll
    for (int j = 0; j < 4; j++) acc[i][j] = 0.f;

  const uint4* X4 = (const uint4*)Xb;
  const float4* W4 = (const float4*)W;
  for (int c0 = 0; c0 < 512; c0 += 16) {
    {
      int row = t >> 1, half = t & 1;
      uint4 a = X4[(size_t)(m0 + row) * 64 + (c0 >> 3) + half];
      int cb = half*8;
      A_s[cb+0][row] = blo(a.x); A_s[cb+1][row] = bhi(a.x);
      A_s[cb+2][row] = blo(a.y); A_s[cb+3][row] = bhi(a.y);
      A_s[cb+4][row] = blo(a.z); A_s[cb+5][row] = bhi(a.z);
      A_s[cb+6][row] = blo(a.w); A_s[cb+7][row] = bhi(a.w);
    }
    {
      int row = t >> 2, quad = t & 3;
      float4 w = W4[(size_t)(o0 + row) * 128 + (c0 >> 2) + quad];
      W_s[quad*4+0][row] = w.x; W_s[quad*4+1][row] = w.y;
      W_s[quad*4+2][row] = w.z; W_s[quad*4+3][row] = w.w;
    }
    __syncthreads();
    #pragma unroll
    for (int kk = 0; kk < 16; kk++) {
      float4 a0 = *(const float4*)&A_s[kk][tm];
      float4 a1 = *(const float4*)&A_s[kk][tm + 4];
      float4 w0 = *(const float4*)&W_s[kk][to];
      float am[8] = {a0.x,a0.y,a0.z,a0.w,a1.x,a1.y,a1.z,a1.w};
      float wn[4] = {w0.x,w0.y,w0.z,w0.w};
      #pragma unroll
      for (int i = 0; i < 8; i++)
        #pragma unroll
        for (int j = 0; j < 4; j++) acc[i][j] += am[i] * wn[j];
    }
    __syncthreads();
  }
  float4 bb = *(const float4*)&bias[o0 + to];
  #pragma unroll
  for (int i = 0; i < 8; i++) {
    int m = m0 + tm + i;
    float4 r = make_float4(acc[i][0]+bb.x, acc[i][1]+bb.y, acc[i][2]+bb.z, acc[i][3]+bb.w);
    *(float4*)&out[(size_t)m*512 + o0 + to] = r;
  }
}

extern "C" void kernel_launch(void* const* d_in, const int* in_sizes, int n_in,
                              void* d_out, int out_size, void* d_ws, size_t ws_size,
                              hipStream_t stream)
{
  (void)in_sizes; (void)n_in; (void)out_size; (void)ws_size;
  const float* node   = (const float*)d_in[0];
  const float* edge   = (const float*)d_in[1];
  const unsigned char* mask = (const unsigned char*)d_in[2];
  const float* qkv_w  = (const float*)d_in[3];
  const float* proj_w = (const float*)d_in[4];
  const float* proj_b = (const float*)d_in[5];
  const float* rw     = (const float*)d_in[6];
  const float* rb     = (const float*)d_in[7];
  const float* ew     = (const float*)d_in[8];
  const float* eb     = (const float*)d_in[9];
  const float* fcw    = (const float*)d_in[10];
  const float* fcb    = (const float*)d_in[11];

  float* out_node = (float*)d_out;
  float* out_edge = out_node + (size_t)16*256*512;

  // workspace: 16 MB total (bf16 intermediates)
  char* ws = (char*)d_ws;
  unsigned short* qb  = (unsigned short*)(ws);                    // 4 MB
  uint2*          ktq = (uint2*)         (ws + 4u*1024*1024);     // 4 MB
  uint2*          vq  = (uint2*)         (ws + 8u*1024*1024);     // 4 MB
  unsigned short* tmpb= (unsigned short*)(ws + 12u*1024*1024);    // 4 MB

  qkv_gemm <<<dim3(32, 24, 1), 256, 0, stream>>>(node, qkv_w, qb, ktq, vq);
  fused_attn<<<dim3(512, 1, 1), 1024, 0, stream>>>(qb, ktq, vq, edge, mask,
                                                   rw, rb, ew, eb, fcw, fcb,
                                                   out_edge, tmpb);
  proj_gemm<<<dim3(32, 8, 1), 256, 0, stream>>>(tmpb, proj_w, proj_b, out_node);
}